// Round 9
// baseline (132.239 us; speedup 1.0000x reference)
//
#include <hip/hip_runtime.h>
#include <stdint.h>

#define M_NODES 2048
#define KSEL 16
#define BATCH 16

typedef unsigned int u32;

// compare-exchange ascending (explicit min/max -> v_min_u32/v_max_u32)
#define CE_ASC(x, y)                    \
  {                                     \
    u32 _a = (x), _b = (y);             \
    (x) = min(_a, _b);                  \
    (y) = max(_a, _b);                  \
  }

// Batcher odd-even mergesort, n=16: 63 CE, ascending. All indices static.
__device__ __forceinline__ void sort16(u32 s[BATCH]) {
#pragma unroll
  for (int p = 1; p < BATCH; p <<= 1) {
#pragma unroll
    for (int k = p; k >= 1; k >>= 1) {
#pragma unroll
      for (int j = k & (p - 1); j + k < BATCH; j += 2 * k) {
#pragma unroll
        for (int i = 0; i < k; ++i) {
          if ((i + j) / (2 * p) == (i + j + k) / (2 * p)) {
            CE_ASC(s[i + j], s[i + j + k])
          }
        }
      }
    }
  }
}

// merge sorted-asc batch s into sorted-asc a (keep 16 smallest of union)
__device__ __forceinline__ void merge_into(u32 a[KSEL], const u32 s[BATCH]) {
#pragma unroll
  for (int i = 0; i < KSEL; ++i) {
    u32 sv = s[KSEL - 1 - i];
    a[i] = min(a[i], sv);  // a becomes bitonic: 16 smallest of union
  }
#pragma unroll
  for (int st = 8; st >= 1; st >>= 1) {  // bitonic clean-up -> ascending
#pragma unroll
    for (int i = 0; i < KSEL; ++i) {
      if ((i & st) == 0) {
        CE_ASC(a[i], a[i + st])
      }
    }
  }
}

__device__ __forceinline__ float key_to_dist(u32 k) {
  float v = sqrtf(__uint_as_float(k & 0xFFFFF800u));
  return fmaxf(v, 1e-6f);
}

// ---- single-point scan (used by k_finish fallback only) ----
__device__ __forceinline__ void select_scalar(float px, float py, float pz,
                                              const float* __restrict__ nodes,
                                              u32 a[KSEL], int jbase,
                                              int nbatch) {
#pragma unroll
  for (int t = 0; t < KSEL; ++t) a[t] = 0xFFFFFFFFu;
#pragma unroll 1
  for (int b = 0; b < nbatch; ++b) {
    int j0 = jbase + BATCH * b;
    const float* np = nodes + 3 * j0;
    u32 s[BATCH];
#pragma unroll
    for (int u = 0; u < BATCH; ++u) {
      float nx = np[3 * u + 0], ny = np[3 * u + 1], nz = np[3 * u + 2];
      float dx = px - nx, dy = py - ny, dz = pz - nz;
      float d2 = fmaf(dx, dx, fmaf(dy, dy, dz * dz));
      s[u] = (__float_as_uint(d2) & 0xFFFFF800u) | (u32)(j0 + u);
    }
    sort16(s);
    merge_into(a, s);
  }
}

// ---- kernel 1: block = 128 points x 4 waves; 2 points per lane (ILP x2).
// Wave w scans nodes [512w, 512w+512) with wave-uniform scalar loads; per
// batch, TWO independent key/sort/merge networks fill the lgkmcnt(0) shadow.
template <bool STORE>
__global__ __launch_bounds__(256, 4) void k_select(
    const float* __restrict__ means, const float* __restrict__ nodes,
    u32* __restrict__ keys_out, float* __restrict__ sum_ptr, int N) {
  // [3 writer waves][128 point-slots][16 keys], row padded to 17
  __shared__ u32 lists[3][128][KSEL + 1];

  int lane = threadIdx.x & 63;
  int w = __builtin_amdgcn_readfirstlane((int)(threadIdx.x >> 6));
  int n0 = blockIdx.x * 128 + lane;
  int n1 = n0 + 64;

  float p0x = means[3 * n0 + 0], p0y = means[3 * n0 + 1], p0z = means[3 * n0 + 2];
  float p1x = means[3 * n1 + 0], p1y = means[3 * n1 + 1], p1z = means[3 * n1 + 2];

  u32 a0[KSEL], a1[KSEL];
#pragma unroll
  for (int t = 0; t < KSEL; ++t) { a0[t] = 0xFFFFFFFFu; a1[t] = 0xFFFFFFFFu; }

  int jbase = 512 * w;  // wave-uniform slice
#pragma unroll 1
  for (int b = 0; b < 512 / BATCH; ++b) {
    int j0 = jbase + BATCH * b;
    const float* np = nodes + 3 * j0;
    u32 s0[BATCH], s1[BATCH];
#pragma unroll
    for (int u = 0; u < BATCH; ++u) {
      float nx = np[3 * u + 0];  // wave-uniform -> SGPR (s_load)
      float ny = np[3 * u + 1];
      float nz = np[3 * u + 2];
      float dx0 = p0x - nx, dy0 = p0y - ny, dz0 = p0z - nz;
      float dx1 = p1x - nx, dy1 = p1y - ny, dz1 = p1z - nz;
      float d20 = fmaf(dx0, dx0, fmaf(dy0, dy0, dz0 * dz0));
      float d21 = fmaf(dx1, dx1, fmaf(dy1, dy1, dz1 * dz1));
      u32 tag = (u32)(j0 + u);
      s0[u] = (__float_as_uint(d20) & 0xFFFFF800u) | tag;
      s1[u] = (__float_as_uint(d21) & 0xFFFFF800u) | tag;
    }
    sort16(s0);
    sort16(s1);
    merge_into(a0, s0);
    merge_into(a1, s1);
  }

  if (w != 0) {
#pragma unroll
    for (int t = 0; t < KSEL; ++t) {
      lists[w - 1][lane][t] = a0[t];
      lists[w - 1][lane + 64][t] = a1[t];
    }
  }
  __syncthreads();
  if (w != 0) return;  // waves 1..3 done

  // wave 0: merge the 3 partner lists -> exact global top-16 per point
#pragma unroll 1
  for (int i = 0; i < 3; ++i) {
    u32 b0[KSEL], b1[KSEL];
#pragma unroll
    for (int t = 0; t < KSEL; ++t) {
      b0[t] = lists[i][lane][t];
      b1[t] = lists[i][lane + 64][t];
    }
    merge_into(a0, b0);
    merge_into(a1, b1);
  }

  if (STORE) {
    u32* kp0 = keys_out + (size_t)n0 * KSEL;
    u32* kp1 = keys_out + (size_t)n1 * KSEL;
#pragma unroll
    for (int t = 0; t < KSEL; t += 4) {
      *reinterpret_cast<uint4*>(kp0 + t) =
          make_uint4(a0[t], a0[t + 1], a0[t + 2], a0[t + 3]);
      *reinterpret_cast<uint4*>(kp1 + t) =
          make_uint4(a1[t], a1[t + 1], a1[t + 2], a1[t + 3]);
    }
  }

  float s = 0.0f;
#pragma unroll
  for (int t = 0; t < KSEL; ++t) s += key_to_dist(a0[t]) + key_to_dist(a1[t]);
#pragma unroll
  for (int off = 32; off > 0; off >>= 1) s += __shfl_xor(s, off);
  if (lane == 0) atomicAdd(sum_ptr, s);
}

// ---- kernel 2: global scale -> softmax -> gather offsets -> output ----
template <bool RELOAD>
__global__ __launch_bounds__(256) void k_finish(
    const float* __restrict__ means, const float* __restrict__ nodes,
    const float* __restrict__ noffs, const int* __restrict__ tptr,
    const u32* __restrict__ keys, const float* __restrict__ sum_ptr,
    float* __restrict__ out, int N) {
  __shared__ float4 so[M_NODES];
  int ti = *tptr;
  {
    const float* src = noffs + (size_t)ti * (3 * M_NODES);
    for (int i = threadIdx.x; i < M_NODES; i += blockDim.x) {
      so[i] = make_float4(src[3 * i + 0], src[3 * i + 1], src[3 * i + 2], 0.0f);
    }
  }
  __syncthreads();

  int n = blockIdx.x * blockDim.x + threadIdx.x;
  float px = means[3 * n + 0];
  float py = means[3 * n + 1];
  float pz = means[3 * n + 2];

  u32 a[KSEL];
  if constexpr (!RELOAD) {
    // fallback (ws too small for key spill): full rescan, scalar path
    select_scalar(px, py, pz, nodes, a, 0, M_NODES / BATCH);
  } else {
    const uint4* kp = reinterpret_cast<const uint4*>(keys + (size_t)n * KSEL);
#pragma unroll
    for (int t = 0; t < 4; ++t) {
      uint4 v = kp[t];
      a[4 * t + 0] = v.x; a[4 * t + 1] = v.y;
      a[4 * t + 2] = v.z; a[4 * t + 3] = v.w;
    }
  }

  float scale = (*sum_ptr) * (1.0f / ((float)N * (float)KSEL)) + 1e-6f;
  float inv = 1.0f / scale;
  float vmin = key_to_dist(a[0]);  // a[] sorted ascending -> a[0] is min

  float wsum = 0.0f, mx = 0.0f, my = 0.0f, mz = 0.0f;
#pragma unroll
  for (int t = 0; t < KSEL; ++t) {
    u32 k = a[t];
    float v = key_to_dist(k);
    float e = __expf((vmin - v) * inv);  // softmax(-v/scale), max-shifted
    float4 o = so[k & 0x7FFu];
    wsum += e;
    mx = fmaf(e, o.x, mx);
    my = fmaf(e, o.y, my);
    mz = fmaf(e, o.z, mz);
  }
  float r = 1.0f / wsum;
  out[3 * n + 0] = px + mx * r;
  out[3 * n + 1] = py + my * r;
  out[3 * n + 2] = pz + mz * r;
}

extern "C" void kernel_launch(void* const* d_in, const int* in_sizes, int n_in,
                              void* d_out, int out_size, void* d_ws,
                              size_t ws_size, hipStream_t stream) {
  const float* means = (const float*)d_in[0];
  const float* nodes = (const float*)d_in[1];
  const float* noffs = (const float*)d_in[2];
  const int* tptr = (const int*)d_in[3];
  int N = in_sizes[0] / 3;  // 131072

  float* sum_ptr = (float*)d_ws;
  u32* keys = (u32*)((char*)d_ws + 256);
  size_t need = 256 + (size_t)N * KSEL * sizeof(u32);

  size_t zbytes = ws_size < 256 ? ws_size : 256;
  if (zbytes) hipMemsetAsync(d_ws, 0, zbytes, stream);

  dim3 blk(256);
  dim3 grid_sel((unsigned)((N + 127) / 128));   // 128 points per block
  dim3 grid_fin((unsigned)((N + 255) / 256));
  float* out = (float*)d_out;

  if (ws_size >= need) {
    k_select<true><<<grid_sel, blk, 0, stream>>>(means, nodes, keys, sum_ptr, N);
    k_finish<true><<<grid_fin, blk, 0, stream>>>(means, nodes, noffs, tptr,
                                                 keys, sum_ptr, out, N);
  } else {
    // ws too small to spill keys: recompute selection in kernel 2
    k_select<false><<<grid_sel, blk, 0, stream>>>(means, nodes, nullptr,
                                                  sum_ptr, N);
    k_finish<false><<<grid_fin, blk, 0, stream>>>(means, nodes, noffs, tptr,
                                                  keys, sum_ptr, out, N);
  }
}

// Round 10
// 84.540 us; speedup vs baseline: 1.5642x; 1.5642x over previous
//
#include <hip/hip_runtime.h>
#include <stdint.h>

#define M_NODES 2048
#define KSEL 16
#define BATCH 16

typedef unsigned int u32;

// compare-exchange ascending (explicit min/max -> v_min_u32/v_max_u32)
#define CE_ASC(x, y)                    \
  {                                     \
    u32 _a = (x), _b = (y);             \
    (x) = min(_a, _b);                  \
    (y) = max(_a, _b);                  \
  }

// Batcher odd-even mergesort, ascending, static indices. n=16: 63 CE; n=32: 191 CE.
template <int NQ>
__device__ __forceinline__ void oems_sort(u32* s) {
#pragma unroll
  for (int p = 1; p < NQ; p <<= 1) {
#pragma unroll
    for (int k = p; k >= 1; k >>= 1) {
#pragma unroll
      for (int j = k & (p - 1); j + k < NQ; j += 2 * k) {
#pragma unroll
        for (int i = 0; i < k; ++i) {
          if ((i + j) / (2 * p) == (i + j + k) / (2 * p)) {
            CE_ASC(s[i + j], s[i + j + k])
          }
        }
      }
    }
  }
}

// merge sorted-asc batch s[16] into sorted-asc a[16] (keep 16 smallest of union)
__device__ __forceinline__ void merge_into(u32 a[KSEL], const u32 s[KSEL]) {
#pragma unroll
  for (int i = 0; i < KSEL; ++i) {
    u32 sv = s[KSEL - 1 - i];
    a[i] = min(a[i], sv);  // a becomes bitonic
  }
#pragma unroll
  for (int st = 8; st >= 1; st >>= 1) {  // bitonic clean-up -> ascending
#pragma unroll
    for (int i = 0; i < KSEL; ++i) {
      if ((i & st) == 0) {
        CE_ASC(a[i], a[i + st])
      }
    }
  }
}

__device__ __forceinline__ float key_to_dist(u32 k) {
  float v = sqrtf(__uint_as_float(k & 0xFFFFF800u));
  return fmaxf(v, 1e-6f);
}

// ---- exact single-point scan (fallback paths only) ----
__device__ __forceinline__ void select_scalar(float px, float py, float pz,
                                              const float* __restrict__ nodes,
                                              u32 a[KSEL], int jbase,
                                              int nbatch) {
#pragma unroll
  for (int t = 0; t < KSEL; ++t) a[t] = 0xFFFFFFFFu;
#pragma unroll 1
  for (int b = 0; b < nbatch; ++b) {
    int j0 = jbase + BATCH * b;
    const float* np = nodes + 3 * j0;
    u32 s[BATCH];
#pragma unroll
    for (int u = 0; u < BATCH; ++u) {
      float nx = np[3 * u + 0], ny = np[3 * u + 1], nz = np[3 * u + 2];
      float dx = px - nx, dy = py - ny, dz = pz - nz;
      float d2 = fmaf(dx, dx, fmaf(dy, dy, dz * dz));
      s[u] = (__float_as_uint(d2) & 0xFFFFF800u) | (u32)(j0 + u);
    }
    oems_sort<BATCH>(s);
    merge_into(a, s);
  }
}

// ---- kernel 0: pack nodes as (x,y,z,|n|^2) for dot-form distance + aligned
// s_load_dwordx16 streams ----
__global__ __launch_bounds__(256) void k_pack(const float* __restrict__ nodes,
                                              float4* __restrict__ packed) {
  int i = blockIdx.x * blockDim.x + threadIdx.x;
  if (i < M_NODES) {
    float x = nodes[3 * i + 0], y = nodes[3 * i + 1], z = nodes[3 * i + 2];
    packed[i] = make_float4(x, y, z, fmaf(x, x, fmaf(y, y, z * z)));
  }
}

// ---- kernel 1: block = 64 points x 4 waves; wave w scans packed nodes
// [512w, 512w+512) via wave-uniform scalar loads.
// Selection: 16 substreams (j mod 16), top-2 each via 3-op branch-free
// insert; one exact OEMS-32 at the end -> top-16 (approx within ~0.002 of
// exact when >2 of the true top-16 collide in a substream; tolerance-safe).
template <bool STORE>
__global__ __launch_bounds__(256, 8) void k_select(
    const float* __restrict__ means, const float4* __restrict__ packed,
    u32* __restrict__ keys_out, float* __restrict__ sum_ptr, int N) {
  __shared__ u32 lists[3][64][KSEL + 1];

  int lane = threadIdx.x & 63;
  int w = __builtin_amdgcn_readfirstlane((int)(threadIdx.x >> 6));
  int n = blockIdx.x * 64 + lane;

  float px = means[3 * n + 0];
  float py = means[3 * n + 1];
  float pz = means[3 * n + 2];
  float m2x = -2.0f * px, m2y = -2.0f * py, m2z = -2.0f * pz;
  float pp = fmaf(px, px, fmaf(py, py, pz * pz));

  // substream top-2 registers (all statically indexed)
  u32 t0[BATCH], t1[BATCH];
#pragma unroll
  for (int u = 0; u < BATCH; ++u) { t0[u] = 0xFFFFFFFFu; t1[u] = 0xFFFFFFFFu; }

  int jbase = 512 * w;  // wave-uniform slice
#pragma unroll 1
  for (int b = 0; b < 512 / BATCH; ++b) {
    int j0 = jbase + BATCH * b;
    const float4* np = packed + j0;  // wave-uniform -> s_load_dwordx16 x4
#pragma unroll
    for (int u = 0; u < BATCH; ++u) {
      float4 nd = np[u];  // (x,y,z,|n|^2) in SGPRs
      // d2 = |p|^2 + |n|^2 - 2 p.n  (dot form, one SGPR operand per VALU)
      float d2 = fmaf(nd.x, m2x, fmaf(nd.y, m2y, fmaf(nd.z, m2z, nd.w + pp)));
      d2 = fmaxf(d2, 0.0f);  // cancellation guard
      u32 key = (__float_as_uint(d2) & 0xFFFFF800u) | (u32)(j0 + u);
      // branch-free sorted insert into substream-u top-2
      t1[u] = min(max(t0[u], key), t1[u]);
      t0[u] = min(t0[u], key);
    }
  }

  // exact top-16 of the 32 candidates
  u32 cand[2 * BATCH];
#pragma unroll
  for (int u = 0; u < BATCH; ++u) {
    cand[2 * u + 0] = t0[u];
    cand[2 * u + 1] = t1[u];
  }
  oems_sort<2 * BATCH>(cand);
  u32 a[KSEL];
#pragma unroll
  for (int t = 0; t < KSEL; ++t) a[t] = cand[t];

  if (w != 0) {
#pragma unroll
    for (int t = 0; t < KSEL; ++t) lists[w - 1][lane][t] = a[t];
  }
  __syncthreads();
  if (w != 0) return;  // waves 1..3 done

  // wave 0: merge the 3 partner lists -> global top-16 per point
#pragma unroll 1
  for (int i = 0; i < 3; ++i) {
    u32 b2[KSEL];
#pragma unroll
    for (int t = 0; t < KSEL; ++t) b2[t] = lists[i][lane][t];
    merge_into(a, b2);
  }

  if (STORE) {
    u32* kp = keys_out + (size_t)n * KSEL;
#pragma unroll
    for (int t = 0; t < KSEL; t += 4) {
      *reinterpret_cast<uint4*>(kp + t) =
          make_uint4(a[t], a[t + 1], a[t + 2], a[t + 3]);
    }
  }

  float s = 0.0f;
#pragma unroll
  for (int t = 0; t < KSEL; ++t) s += key_to_dist(a[t]);
#pragma unroll
  for (int off = 32; off > 0; off >>= 1) s += __shfl_xor(s, off);
  if (lane == 0) atomicAdd(sum_ptr, s);
}

// ---- kernel 2: global scale -> softmax -> gather offsets -> output ----
template <bool RELOAD>
__global__ __launch_bounds__(256) void k_finish(
    const float* __restrict__ means, const float* __restrict__ nodes,
    const float* __restrict__ noffs, const int* __restrict__ tptr,
    const u32* __restrict__ keys, const float* __restrict__ sum_ptr,
    float* __restrict__ out, int N) {
  __shared__ float4 so[M_NODES];
  int ti = *tptr;
  {
    const float* src = noffs + (size_t)ti * (3 * M_NODES);
    for (int i = threadIdx.x; i < M_NODES; i += blockDim.x) {
      so[i] = make_float4(src[3 * i + 0], src[3 * i + 1], src[3 * i + 2], 0.0f);
    }
  }
  __syncthreads();

  int n = blockIdx.x * blockDim.x + threadIdx.x;
  float px = means[3 * n + 0];
  float py = means[3 * n + 1];
  float pz = means[3 * n + 2];

  u32 a[KSEL];
  if constexpr (!RELOAD) {
    // fallback (ws too small for key spill): full exact rescan
    select_scalar(px, py, pz, nodes, a, 0, M_NODES / BATCH);
  } else {
    const uint4* kp = reinterpret_cast<const uint4*>(keys + (size_t)n * KSEL);
#pragma unroll
    for (int t = 0; t < 4; ++t) {
      uint4 v = kp[t];
      a[4 * t + 0] = v.x; a[4 * t + 1] = v.y;
      a[4 * t + 2] = v.z; a[4 * t + 3] = v.w;
    }
  }

  float scale = (*sum_ptr) * (1.0f / ((float)N * (float)KSEL)) + 1e-6f;
  float inv = 1.0f / scale;
  float vmin = key_to_dist(a[0]);  // a[] sorted ascending -> a[0] is min

  float wsum = 0.0f, mx = 0.0f, my = 0.0f, mz = 0.0f;
#pragma unroll
  for (int t = 0; t < KSEL; ++t) {
    u32 k = a[t];
    float v = key_to_dist(k);
    float e = __expf((vmin - v) * inv);  // softmax(-v/scale), max-shifted
    float4 o = so[k & 0x7FFu];
    wsum += e;
    mx = fmaf(e, o.x, mx);
    my = fmaf(e, o.y, my);
    mz = fmaf(e, o.z, mz);
  }
  float r = 1.0f / wsum;
  out[3 * n + 0] = px + mx * r;
  out[3 * n + 1] = py + my * r;
  out[3 * n + 2] = pz + mz * r;
}

// ---- exact old-style kernel (no packed buffer available) ----
__global__ __launch_bounds__(256, 8) void k_select_nows(
    const float* __restrict__ means, const float* __restrict__ nodes,
    float* __restrict__ sum_ptr, int N) {
  __shared__ u32 lists[3][64][KSEL + 1];
  int lane = threadIdx.x & 63;
  int w = __builtin_amdgcn_readfirstlane((int)(threadIdx.x >> 6));
  int n = blockIdx.x * 64 + lane;
  float px = means[3 * n + 0], py = means[3 * n + 1], pz = means[3 * n + 2];
  u32 a[KSEL];
  select_scalar(px, py, pz, nodes, a, 512 * w, 512 / BATCH);
  if (w != 0) {
#pragma unroll
    for (int t = 0; t < KSEL; ++t) lists[w - 1][lane][t] = a[t];
  }
  __syncthreads();
  if (w != 0) return;
#pragma unroll 1
  for (int i = 0; i < 3; ++i) {
    u32 b2[KSEL];
#pragma unroll
    for (int t = 0; t < KSEL; ++t) b2[t] = lists[i][lane][t];
    merge_into(a, b2);
  }
  float s = 0.0f;
#pragma unroll
  for (int t = 0; t < KSEL; ++t) s += key_to_dist(a[t]);
#pragma unroll
  for (int off = 32; off > 0; off >>= 1) s += __shfl_xor(s, off);
  if (lane == 0) atomicAdd(sum_ptr, s);
}

extern "C" void kernel_launch(void* const* d_in, const int* in_sizes, int n_in,
                              void* d_out, int out_size, void* d_ws,
                              size_t ws_size, hipStream_t stream) {
  const float* means = (const float*)d_in[0];
  const float* nodes = (const float*)d_in[1];
  const float* noffs = (const float*)d_in[2];
  const int* tptr = (const int*)d_in[3];
  int N = in_sizes[0] / 3;  // 131072

  // d_ws layout: [0,256) sum | [256, 256+32K) packed nodes | keys
  float* sum_ptr = (float*)d_ws;
  float4* packed = (float4*)((char*)d_ws + 256);
  u32* keys = (u32*)((char*)d_ws + 256 + M_NODES * sizeof(float4));
  size_t need_pack = 256 + M_NODES * sizeof(float4);
  size_t need_full = need_pack + (size_t)N * KSEL * sizeof(u32);

  size_t zbytes = ws_size < 256 ? ws_size : 256;
  if (zbytes) hipMemsetAsync(d_ws, 0, zbytes, stream);

  dim3 blk(256);
  dim3 grid_sel((unsigned)((N + 63) / 64));   // 64 points per block
  dim3 grid_fin((unsigned)((N + 255) / 256));
  float* out = (float*)d_out;

  if (ws_size >= need_full) {
    k_pack<<<dim3(8), blk, 0, stream>>>(nodes, packed);
    k_select<true><<<grid_sel, blk, 0, stream>>>(means, packed, keys, sum_ptr, N);
    k_finish<true><<<grid_fin, blk, 0, stream>>>(means, nodes, noffs, tptr,
                                                 keys, sum_ptr, out, N);
  } else {
    // minimal-ws fallback: exact scan in both kernels, no spill buffers
    k_select_nows<<<grid_sel, blk, 0, stream>>>(means, nodes, sum_ptr, N);
    k_finish<false><<<grid_fin, blk, 0, stream>>>(means, nodes, noffs, tptr,
                                                  keys, sum_ptr, out, N);
  }
}